// Round 1
// baseline (548.773 us; speedup 1.0000x reference)
//
#include <hip/hip_runtime.h>

#define ADAGRAD_EPS 1e-10f

// Kernel 1: initialize outputs: out_w = weights, out_m = moments.
// Pure bandwidth: 2 * 128 MB read + 2 * 128 MB write.
__global__ void copy_init_kernel(const float4* __restrict__ w4,
                                 const float4* __restrict__ m4,
                                 float4* __restrict__ ow4,
                                 float4* __restrict__ om4,
                                 long long n4) {
    long long i = (long long)blockIdx.x * blockDim.x + threadIdx.x;
    long long stride = (long long)gridDim.x * blockDim.x;
    for (; i < n4; i += stride) {
        ow4[i] = w4[i];
        om4[i] = m4[i];
    }
}

// Kernel 2: out_m[idx[row]*64 + d] += g[row*64 + d]^2 for valid rows.
// One thread per element; 64 threads share one index (broadcast load).
__global__ void scatter_m_kernel(const float* __restrict__ g,
                                 const int* __restrict__ idx,
                                 const int* __restrict__ valid_count,
                                 float* __restrict__ out_m) {
    int vc = *valid_count;
    int t = blockIdx.x * blockDim.x + threadIdx.x;
    int row = t >> 6;
    if (row >= vc) return;
    float gv = g[t];
    int i = idx[row];
    atomicAdd(&out_m[(long long)i * 64 + (t & 63)], gv * gv);
}

// Kernel 3: out_w[idx[row]*64 + d] += -lr * g / (sqrt(m_new) + eps).
// Runs after kernel 2 completes -> out_m is fully accumulated.
__global__ void update_w_kernel(const float* __restrict__ g,
                                const int* __restrict__ idx,
                                const int* __restrict__ valid_count,
                                const float* __restrict__ lr_p,
                                const float* __restrict__ out_m,
                                float* __restrict__ out_w) {
    int vc = *valid_count;
    int t = blockIdx.x * blockDim.x + threadIdx.x;
    int row = t >> 6;
    if (row >= vc) return;
    int d = t & 63;
    float gv = g[t];
    int i = idx[row];
    long long off = (long long)i * 64 + d;
    float m = out_m[off];
    float lr = *lr_p;
    float upd = -lr * gv / (sqrtf(m) + ADAGRAD_EPS);
    atomicAdd(&out_w[off], upd);
}

extern "C" void kernel_launch(void* const* d_in, const int* in_sizes, int n_in,
                              void* d_out, int out_size, void* d_ws, size_t ws_size,
                              hipStream_t stream) {
    const float* g  = (const float*)d_in[0];   // [N, 64]
    const float* w  = (const float*)d_in[1];   // [V, 64]
    const float* m  = (const float*)d_in[2];   // [V, 64]
    const int*   idx = (const int*)d_in[3];    // [N]
    const float* lr  = (const float*)d_in[4];  // scalar
    const int*   vc  = (const int*)d_in[5];    // scalar

    long long ND = in_sizes[0];  // N*64
    long long VD = in_sizes[1];  // V*64

    float* out_w = (float*)d_out;
    float* out_m = (float*)d_out + VD;

    // Kernel 1: vectorized copy of both tables into the output buffers.
    long long n4 = VD / 4;
    copy_init_kernel<<<4096, 256, 0, stream>>>(
        (const float4*)w, (const float4*)m, (float4*)out_w, (float4*)out_m, n4);

    // Kernels 2 & 3: one thread per gradient element (64 per row).
    int blocks = (int)((ND + 255) / 256);
    scatter_m_kernel<<<blocks, 256, 0, stream>>>(g, idx, vc, out_m);
    update_w_kernel<<<blocks, 256, 0, stream>>>(g, idx, vc, lr, out_m, out_w);
}

// Round 2
// 467.894 us; speedup vs baseline: 1.1729x; 1.1729x over previous
//
#include <hip/hip_runtime.h>

#define ADAGRAD_EPS 1e-10f

// Per-index linked lists over gradient rows: head[V], next[N] in workspace.
// This removes all per-element atomics (25.6M -> 200k atomicExch).

__global__ void init_head_kernel(int* __restrict__ head, int V) {
    int i = blockIdx.x * blockDim.x + threadIdx.x;
    if (i < V) head[i] = -1;
}

__global__ void build_lists_kernel(const int* __restrict__ idx,
                                   const int* __restrict__ vc_p,
                                   int* __restrict__ head,
                                   int* __restrict__ next) {
    int vc = *vc_p;
    int r = blockIdx.x * blockDim.x + threadIdx.x;
    if (r >= vc) return;
    int i = idx[r];
    next[r] = atomicExch(&head[i], r);
}

// One 16-lane group per vocab row v; each lane owns a float4 (4 of 64 dims).
// Empty list -> pure copy. Non-empty -> walk chain, accumulate sum(g) and
// sum(g^2) in registers, single non-atomic coalesced store of both outputs.
// All lanes of a group share v -> no divergence within the group; next[r]
// loads are wave-broadcast.
__global__ void apply_kernel(const float4* __restrict__ g4,
                             const float4* __restrict__ w4,
                             const float4* __restrict__ m4,
                             const int* __restrict__ head,
                             const int* __restrict__ next,
                             const float* __restrict__ lr_p,
                             float4* __restrict__ ow4,
                             float4* __restrict__ om4,
                             int V) {
    int t = blockIdx.x * blockDim.x + threadIdx.x;
    int v = t >> 4;
    if (v >= V) return;
    int d = t & 15;
    long long off = (long long)v * 16 + d;

    float4 wv = w4[off];
    float4 mv = m4[off];
    int r = head[v];

    if (r < 0) {  // untouched row: plain copy
        ow4[off] = wv;
        om4[off] = mv;
        return;
    }

    float4 s1 = make_float4(0.f, 0.f, 0.f, 0.f);
    float4 s2 = make_float4(0.f, 0.f, 0.f, 0.f);
    while (r >= 0) {
        float4 gv = g4[(long long)r * 16 + d];
        s1.x += gv.x; s1.y += gv.y; s1.z += gv.z; s1.w += gv.w;
        s2.x += gv.x * gv.x; s2.y += gv.y * gv.y;
        s2.z += gv.z * gv.z; s2.w += gv.w * gv.w;
        r = next[r];
    }

    float4 mn;
    mn.x = mv.x + s2.x; mn.y = mv.y + s2.y;
    mn.z = mv.z + s2.z; mn.w = mv.w + s2.w;
    om4[off] = mn;

    float lr = *lr_p;
    float4 wn;
    wn.x = wv.x - lr * s1.x / (sqrtf(mn.x) + ADAGRAD_EPS);
    wn.y = wv.y - lr * s1.y / (sqrtf(mn.y) + ADAGRAD_EPS);
    wn.z = wv.z - lr * s1.z / (sqrtf(mn.z) + ADAGRAD_EPS);
    wn.w = wv.w - lr * s1.w / (sqrtf(mn.w) + ADAGRAD_EPS);
    ow4[off] = wn;
}

extern "C" void kernel_launch(void* const* d_in, const int* in_sizes, int n_in,
                              void* d_out, int out_size, void* d_ws, size_t ws_size,
                              hipStream_t stream) {
    const float* g   = (const float*)d_in[0];  // [N, 64]
    const float* w   = (const float*)d_in[1];  // [V, 64]
    const float* m   = (const float*)d_in[2];  // [V, 64]
    const int*   idx = (const int*)d_in[3];    // [N]
    const float* lr  = (const float*)d_in[4];  // scalar
    const int*   vc  = (const int*)d_in[5];    // scalar

    long long ND = in_sizes[0];        // N*64
    long long VD = in_sizes[1];        // V*64
    int N = (int)(ND / 64);
    int V = (int)(VD / 64);

    float* out_w = (float*)d_out;
    float* out_m = (float*)d_out + VD;

    int* head = (int*)d_ws;            // V ints
    int* next = head + V;              // N ints

    init_head_kernel<<<(V + 255) / 256, 256, 0, stream>>>(head, V);

    build_lists_kernel<<<(N + 255) / 256, 256, 0, stream>>>(idx, vc, head, next);

    long long apply_threads = (long long)V * 16;
    apply_kernel<<<(int)((apply_threads + 255) / 256), 256, 0, stream>>>(
        (const float4*)g, (const float4*)w, (const float4*)m,
        head, next, lr, (float4*)out_w, (float4*)out_m, V);
}